// Round 3
// baseline (90.140 us; speedup 1.0000x reference)
//
#include <hip/hip_runtime.h>

#define NB 16
#define IN_CH 64
#define OUT_CH 256
#define NUM_NODES 7
#define NUM_LEAVES 8
#define NH 48
#define NW 48
#define NPIX (NH * NW)            // 2304
#define HALO_W 50
#define HALO_ROWS 3
#define LDS_PER_C (HALO_ROWS * HALO_W)   // 150 floats per channel
#define LDS_ELEMS (IN_CH * LDS_PER_C)    // 9600 floats = 38.4 KB

__constant__ float c_gate[16 * 4] = {
    0.f, 0.f, 0.f, 0.f,
    0.f, 0.f, 0.f, 1.f,
    0.f, 1.f, 0.f, -1.f,
    0.f, 1.f, 0.f, 0.f,
    0.f, 0.f, 1.f, -1.f,
    0.f, 0.f, 1.f, 0.f,
    0.f, 1.f, 1.f, -2.f,
    0.f, 1.f, 1.f, -1.f,
    1.f, -1.f, -1.f, 1.f,
    1.f, -1.f, -1.f, 2.f,
    1.f, 0.f, -1.f, 0.f,
    1.f, 0.f, -1.f, 1.f,
    1.f, -1.f, 0.f, 0.f,
    1.f, -1.f, 0.f, 1.f,
    1.f, 0.f, 0.f, -1.f,
    1.f, 0.f, 0.f, 0.f
};

// w[o][n][4] = softmax(logits[o,n,:]) @ GATE_COEFF   (1792 rows)
__global__ __launch_bounds__(256) void prep_w_kernel(
    const float* __restrict__ logits, float* __restrict__ w)
{
    int t = blockIdx.x * 256 + threadIdx.x;
    if (t >= OUT_CH * NUM_NODES) return;
    const float* lg = logits + (size_t)t * 16;

    float m = lg[0];
#pragma unroll
    for (int g = 1; g < 16; ++g) m = fmaxf(m, lg[g]);
    float e16[16];
    float s = 0.f;
#pragma unroll
    for (int g = 0; g < 16; ++g) { e16[g] = expf(lg[g] - m); s += e16[g]; }
    float inv = 1.f / s;

    float w0 = 0.f, w1 = 0.f, w2 = 0.f, w3 = 0.f;
#pragma unroll
    for (int g = 0; g < 16; ++g) {
        float p = e16[g] * inv;
        w0 += p * c_gate[g * 4 + 0];
        w1 += p * c_gate[g * 4 + 1];
        w2 += p * c_gate[g * 4 + 2];
        w3 += p * c_gate[g * 4 + 3];
    }
    reinterpret_cast<float4*>(w)[t] = make_float4(w0, w1, w2, w3);
}

// Main kernel: block = (output row r0, batch b). Stage 3x50x64ch halo in LDS,
// then loop over all 256 output channels (4 waves x 64 iterations).
// Lanes <-> pixel columns: LDS gathers are consecutive (conflict-free),
// leaf indices / weights are wave-uniform (scalar loads).
__global__ __launch_bounds__(256) void ltc_kernel(
    const float* __restrict__ x,        // [B][64][48][48]
    const int*   __restrict__ leaf_idx, // [OUT_CH][8]
    const float* __restrict__ w,        // [OUT_CH][7][4]
    float*       __restrict__ out)      // [B][OUT_CH][48][48]
{
    __shared__ float lds[LDS_ELEMS];

    const int r0 = blockIdx.x;          // 0..47
    const int b  = blockIdx.y;          // 0..15
    const int tid = threadIdx.x;

    // ---- stage halo (with zero padding) ----
    const float* xb = x + (size_t)b * IN_CH * NPIX;
    for (int e = tid; e < LDS_ELEMS; e += 256) {
        int c   = e / LDS_PER_C;
        int rem = e - c * LDS_PER_C;
        int rr  = rem / HALO_W;          // 0..2
        int cc  = rem - rr * HALO_W;     // 0..49
        int gr  = r0 + rr - 1;
        int gc  = cc - 1;
        float v = 0.f;
        if ((unsigned)gr < NH && (unsigned)gc < NW)
            v = xb[(c * NH + gr) * NW + gc];
        lds[e] = v;
    }
    __syncthreads();

    // ---- compute: each wave walks 64 output channels ----
    const int lane = tid & 63;
    const int wid  = __builtin_amdgcn_readfirstlane(tid >> 6);  // 0..3
    const bool act = lane < NW;

    float* outb = out + (size_t)b * OUT_CH * NPIX + r0 * NW + lane;

#pragma unroll 2
    for (int i = 0; i < 64; ++i) {
        const int o = (i << 2) | wid;    // wave-uniform

        float vl[NUM_LEAVES];
#pragma unroll
        for (int l = 0; l < NUM_LEAVES; ++l) {
            int idx = leaf_idx[o * NUM_LEAVES + l];   // scalar load
            int c  = idx / 9;
            int k  = idx - c * 9;
            int di = k / 3;
            int dj = k - di * 3;
            vl[l] = lds[c * LDS_PER_C + di * HALO_W + dj + lane];
        }

        const float4* wo = reinterpret_cast<const float4*>(w + o * NUM_NODES * 4);
        float4 w0 = wo[0], w1 = wo[1], w2 = wo[2], w3 = wo[3];
        float4 w4 = wo[4], w5 = wo[5], w6 = wo[6];

        float t0 = w0.x + w0.y * vl[0] + w0.z * vl[1] + w0.w * (vl[0] * vl[1]);
        float t1 = w1.x + w1.y * vl[2] + w1.z * vl[3] + w1.w * (vl[2] * vl[3]);
        float t2 = w2.x + w2.y * vl[4] + w2.z * vl[5] + w2.w * (vl[4] * vl[5]);
        float t3 = w3.x + w3.y * vl[6] + w3.z * vl[7] + w3.w * (vl[6] * vl[7]);

        float u0 = w4.x + w4.y * t0 + w4.z * t1 + w4.w * (t0 * t1);
        float u1 = w5.x + w5.y * t2 + w5.z * t3 + w5.w * (t2 * t3);

        float y  = w6.x + w6.y * u0 + w6.z * u1 + w6.w * (u0 * u1);

        if (act) outb[(size_t)o * NPIX] = y;
    }
}

extern "C" void kernel_launch(void* const* d_in, const int* in_sizes, int n_in,
                              void* d_out, int out_size, void* d_ws, size_t ws_size,
                              hipStream_t stream) {
    const float* x        = (const float*)d_in[0];
    const float* logits   = (const float*)d_in[1];
    const int*   leaf_idx = (const int*)d_in[2];
    float*       out      = (float*)d_out;
    float*       w        = (float*)d_ws;   // 256*7*4 floats = 28,672 B

    prep_w_kernel<<<(OUT_CH * NUM_NODES + 255) / 256, 256, 0, stream>>>(logits, w);

    dim3 grid(NH, NB);
    ltc_kernel<<<grid, 256, 0, stream>>>(x, leaf_idx, w, out);
}

// Round 4
// 70.192 us; speedup vs baseline: 1.2842x; 1.2842x over previous
//
#include <hip/hip_runtime.h>

#define NB 16
#define IN_CH 64
#define OUT_CH 256
#define NUM_NODES 7
#define NUM_LEAVES 8
#define NH 48
#define NW 48
#define NPIX (NH * NW)            // 2304
#define HALO_W 50
#define HALO_ROWS 3
#define LDS_PER_C (HALO_ROWS * HALO_W)   // 150 floats per channel
#define LDS_ELEMS (IN_CH * LDS_PER_C)    // 9600 floats = 38.4 KB

__constant__ float c_gate[16 * 4] = {
    0.f, 0.f, 0.f, 0.f,
    0.f, 0.f, 0.f, 1.f,
    0.f, 1.f, 0.f, -1.f,
    0.f, 1.f, 0.f, 0.f,
    0.f, 0.f, 1.f, -1.f,
    0.f, 0.f, 1.f, 0.f,
    0.f, 1.f, 1.f, -2.f,
    0.f, 1.f, 1.f, -1.f,
    1.f, -1.f, -1.f, 1.f,
    1.f, -1.f, -1.f, 2.f,
    1.f, 0.f, -1.f, 0.f,
    1.f, 0.f, -1.f, 1.f,
    1.f, -1.f, 0.f, 0.f,
    1.f, -1.f, 0.f, 1.f,
    1.f, 0.f, 0.f, -1.f,
    1.f, 0.f, 0.f, 0.f
};

// w[o][n][4] = softmax(logits[o,n,:]) @ GATE_COEFF   (1792 rows)
__global__ __launch_bounds__(256) void prep_w_kernel(
    const float* __restrict__ logits, float* __restrict__ w)
{
    int t = blockIdx.x * 256 + threadIdx.x;
    if (t >= OUT_CH * NUM_NODES) return;
    const float* lg = logits + (size_t)t * 16;

    float m = lg[0];
#pragma unroll
    for (int g = 1; g < 16; ++g) m = fmaxf(m, lg[g]);
    float e16[16];
    float s = 0.f;
#pragma unroll
    for (int g = 0; g < 16; ++g) { e16[g] = expf(lg[g] - m); s += e16[g]; }
    float inv = 1.f / s;

    float w0 = 0.f, w1 = 0.f, w2 = 0.f, w3 = 0.f;
#pragma unroll
    for (int g = 0; g < 16; ++g) {
        float p = e16[g] * inv;
        w0 += p * c_gate[g * 4 + 0];
        w1 += p * c_gate[g * 4 + 1];
        w2 += p * c_gate[g * 4 + 2];
        w3 += p * c_gate[g * 4 + 3];
    }
    reinterpret_cast<float4*>(w)[t] = make_float4(w0, w1, w2, w3);
}

// Main kernel: block = (row r0, batch b), 4 waves. Stage 3x50x64ch halo in LDS.
// Lane l pre-loads metadata for ITS channel o=wid*64+l into VGPRs (once);
// per iteration i the wave broadcasts lane i's metadata via v_readlane
// (pure VALU, no memory latency) and computes channel o=wid*64+i for 48 cols.
__global__ __launch_bounds__(256) void ltc_kernel(
    const float* __restrict__ x,        // [B][64][48][48]
    const int*   __restrict__ leaf_idx, // [OUT_CH][8]
    const float* __restrict__ w,        // [OUT_CH][7][4]
    float*       __restrict__ out)      // [B][OUT_CH][48][48]
{
    __shared__ float lds[LDS_ELEMS + 64];   // +64 pad: lanes 48-63 read OOB harmlessly

    const int r0  = blockIdx.x;          // 0..47
    const int b   = blockIdx.y;          // 0..15
    const int tid = threadIdx.x;

    // ---- stage halo (with zero padding) ----
    const float* xb = x + (size_t)b * IN_CH * NPIX;
    for (int e = tid; e < LDS_ELEMS; e += 256) {
        int c   = e / LDS_PER_C;
        int rem = e - c * LDS_PER_C;
        int rr  = rem / HALO_W;          // 0..2
        int cc  = rem - rr * HALO_W;     // 0..49
        int gr  = r0 + rr - 1;
        int gc  = cc - 1;
        float v = 0.f;
        if ((unsigned)gr < NH && (unsigned)gc < NW)
            v = xb[(c * NH + gr) * NW + gc];
        lds[e] = v;
    }
    __syncthreads();

    const int lane = tid & 63;
    const int wid  = tid >> 6;                 // 0..3 (wave-uniform)
    const int o_l  = (wid << 6) | lane;        // this lane's preload channel

    // ---- per-lane metadata preload (one time) ----
    int offv[8];
    {
        const int4 li0 = reinterpret_cast<const int4*>(leaf_idx)[o_l * 2 + 0];
        const int4 li1 = reinterpret_cast<const int4*>(leaf_idx)[o_l * 2 + 1];
        int idxs[8] = { li0.x, li0.y, li0.z, li0.w, li1.x, li1.y, li1.z, li1.w };
#pragma unroll
        for (int j = 0; j < 8; ++j) {
            int idx = idxs[j];
            int c  = idx / 9;
            int k  = idx - c * 9;
            int di = k / 3;
            int dj = k - di * 3;
            offv[j] = c * LDS_PER_C + di * HALO_W + dj;   // float index into lds
        }
    }
    float wv[28];
    {
        const float4* wp = reinterpret_cast<const float4*>(w + (size_t)o_l * 28);
#pragma unroll
        for (int q = 0; q < 7; ++q) {
            float4 f = wp[q];
            wv[4 * q + 0] = f.x; wv[4 * q + 1] = f.y;
            wv[4 * q + 2] = f.z; wv[4 * q + 3] = f.w;
        }
    }

    const bool act = lane < NW;
    float* outb = out + (size_t)b * OUT_CH * NPIX
                + (size_t)(wid << 6) * NPIX + r0 * NW + lane;

#pragma unroll 2
    for (int i = 0; i < 64; ++i) {
        // broadcast lane i's leaf offsets -> SGPRs, gather from LDS
        float vl[8];
#pragma unroll
        for (int j = 0; j < 8; ++j) {
            int so = __builtin_amdgcn_readlane(offv[j], i);
            vl[j] = lds[so + lane];
        }
        // broadcast lane i's 28 weights
        float ww[28];
#pragma unroll
        for (int q = 0; q < 28; ++q)
            ww[q] = __int_as_float(
                __builtin_amdgcn_readlane(__float_as_int(wv[q]), i));

        // soft-logic tree, 3 FMA per node
        float t0 = fmaf(vl[1], fmaf(ww[ 3], vl[0], ww[ 2]), fmaf(ww[ 1], vl[0], ww[ 0]));
        float t1 = fmaf(vl[3], fmaf(ww[ 7], vl[2], ww[ 6]), fmaf(ww[ 5], vl[2], ww[ 4]));
        float t2 = fmaf(vl[5], fmaf(ww[11], vl[4], ww[10]), fmaf(ww[ 9], vl[4], ww[ 8]));
        float t3 = fmaf(vl[7], fmaf(ww[15], vl[6], ww[14]), fmaf(ww[13], vl[6], ww[12]));
        float u0 = fmaf(t1, fmaf(ww[19], t0, ww[18]), fmaf(ww[17], t0, ww[16]));
        float u1 = fmaf(t3, fmaf(ww[23], t2, ww[22]), fmaf(ww[21], t2, ww[20]));
        float y  = fmaf(u1, fmaf(ww[27], u0, ww[26]), fmaf(ww[25], u0, ww[24]));

        if (act) outb[(size_t)i * NPIX] = y;
    }
}

extern "C" void kernel_launch(void* const* d_in, const int* in_sizes, int n_in,
                              void* d_out, int out_size, void* d_ws, size_t ws_size,
                              hipStream_t stream) {
    const float* x        = (const float*)d_in[0];
    const float* logits   = (const float*)d_in[1];
    const int*   leaf_idx = (const int*)d_in[2];
    float*       out      = (float*)d_out;
    float*       w        = (float*)d_ws;   // 256*7*4 floats = 28,672 B

    prep_w_kernel<<<(OUT_CH * NUM_NODES + 255) / 256, 256, 0, stream>>>(logits, w);

    dim3 grid(NH, NB);
    ltc_kernel<<<grid, 256, 0, stream>>>(x, leaf_idx, w, out);
}

// Round 5
// 38.444 us; speedup vs baseline: 2.3447x; 1.8258x over previous
//
#include <hip/hip_runtime.h>

#define NB 16
#define IN_CH 64
#define OUT_CH 256
#define NH 48
#define NW 48
#define NPIX (NH * NW)                 // 2304
#define ROW_STRIDE 52                  // dwords per staged row (8B-aligned halo layout)
#define CH_STRIDE (4 * ROW_STRIDE)     // 208 dwords per channel (4 halo rows)
#define LDS_DW (IN_CH * CH_STRIDE)     // 13312 dwords = 53,248 B -> 3 blocks/CU
#define NITEMS (IN_CH * 4 * 26)        // 6656 float2 staging items (26 pairs/row)
#define META_F4 9                      // 9 float4 per o: [0..1]=8 int offsets, [2..8]=7 nodes

__constant__ float c_gate[16 * 4] = {
    0.f, 0.f, 0.f, 0.f,
    0.f, 0.f, 0.f, 1.f,
    0.f, 1.f, 0.f, -1.f,
    0.f, 1.f, 0.f, 0.f,
    0.f, 0.f, 1.f, -1.f,
    0.f, 0.f, 1.f, 0.f,
    0.f, 1.f, 1.f, -2.f,
    0.f, 1.f, 1.f, -1.f,
    1.f, -1.f, -1.f, 1.f,
    1.f, -1.f, -1.f, 2.f,
    1.f, 0.f, -1.f, 0.f,
    1.f, 0.f, -1.f, 1.f,
    1.f, -1.f, 0.f, 0.f,
    1.f, -1.f, 0.f, 1.f,
    1.f, 0.f, 0.f, -1.f,
    1.f, 0.f, 0.f, 0.f
};

// Fused metadata prep: records meta[o][36]:
//   dwords 0..7  : int LDS-offset precursor  c*CH_STRIDE + di*ROW_STRIDE + dj
//   dwords 8..35 : 7 nodes x 4 floats = softmax(logits[o,n,:]) @ GATE_COEFF
// grid = 15 blocks x 256: t<2048 -> offsets; 2048<=t<3840 -> weights.
__global__ __launch_bounds__(256) void prep_kernel(
    const float* __restrict__ logits,
    const int*   __restrict__ leaf_idx,
    float*       __restrict__ meta)
{
    int t = blockIdx.x * 256 + threadIdx.x;
    if (t < OUT_CH * 8) {
        int idx = leaf_idx[t];
        int c  = idx / 9;
        int k  = idx - c * 9;
        int di = k / 3;
        int dj = k - di * 3;
        reinterpret_cast<int*>(meta)[(t >> 3) * 36 + (t & 7)] =
            c * CH_STRIDE + di * ROW_STRIDE + dj;
    } else {
        int t2 = t - OUT_CH * 8;
        if (t2 >= OUT_CH * 7) return;
        int o = t2 / 7;
        int n = t2 - o * 7;
        const float* lg = logits + (size_t)t2 * 16;

        float m = lg[0];
#pragma unroll
        for (int g = 1; g < 16; ++g) m = fmaxf(m, lg[g]);
        float e16[16];
        float s = 0.f;
#pragma unroll
        for (int g = 0; g < 16; ++g) { e16[g] = expf(lg[g] - m); s += e16[g]; }
        float inv = 1.f / s;

        float w0 = 0.f, w1 = 0.f, w2 = 0.f, w3 = 0.f;
#pragma unroll
        for (int g = 0; g < 16; ++g) {
            float p = e16[g] * inv;
            w0 += p * c_gate[g * 4 + 0];
            w1 += p * c_gate[g * 4 + 1];
            w2 += p * c_gate[g * 4 + 2];
            w3 += p * c_gate[g * 4 + 3];
        }
        float* mw = meta + o * 36 + 8 + n * 4;
        mw[0] = w0; mw[1] = w1; mw[2] = w2; mw[3] = w3;
    }
}

// One body: prefetch next o's metadata into MN, compute current o from MC.
// 32-lane o-group shares o; metadata duplicated per-lane in VGPRs (no broadcast).
#define LTC_BODY(MC, MN)                                                        \
    {                                                                           \
        _Pragma("unroll")                                                       \
        for (int q = 0; q < 9; ++q) MN[q] = mptr[9 + q];                        \
        const int off0 = __float_as_int(MC[0].x);                               \
        const int off1 = __float_as_int(MC[0].y);                               \
        const int off2 = __float_as_int(MC[0].z);                               \
        const int off3 = __float_as_int(MC[0].w);                               \
        const int off4 = __float_as_int(MC[1].x);                               \
        const int off5 = __float_as_int(MC[1].y);                               \
        const int off6 = __float_as_int(MC[1].z);                               \
        const int off7 = __float_as_int(MC[1].w);                               \
        _Pragma("unroll")                                                       \
        for (int g = 0; g < 3; ++g) {                                           \
            const int bg = bases[g];                                            \
            float v0 = lds[off0 + bg];                                          \
            float v1 = lds[off1 + bg];                                          \
            float v2 = lds[off2 + bg];                                          \
            float v3 = lds[off3 + bg];                                          \
            float v4 = lds[off4 + bg];                                          \
            float v5 = lds[off5 + bg];                                          \
            float v6 = lds[off6 + bg];                                          \
            float v7 = lds[off7 + bg];                                          \
            float t0 = fmaf(v1, fmaf(MC[2].w, v0, MC[2].z), fmaf(MC[2].y, v0, MC[2].x)); \
            float t1 = fmaf(v3, fmaf(MC[3].w, v2, MC[3].z), fmaf(MC[3].y, v2, MC[3].x)); \
            float t2 = fmaf(v5, fmaf(MC[4].w, v4, MC[4].z), fmaf(MC[4].y, v4, MC[4].x)); \
            float t3 = fmaf(v7, fmaf(MC[5].w, v6, MC[5].z), fmaf(MC[5].y, v6, MC[5].x)); \
            float u0 = fmaf(t1, fmaf(MC[6].w, t0, MC[6].z), fmaf(MC[6].y, t0, MC[6].x)); \
            float u1 = fmaf(t3, fmaf(MC[7].w, t2, MC[7].z), fmaf(MC[7].y, t2, MC[7].x)); \
            float y  = fmaf(u1, fmaf(MC[8].w, u0, MC[8].z), fmaf(MC[8].y, u0, MC[8].x)); \
            pbase[opx[g]] = y;                                                  \
        }                                                                       \
        mptr  += 9;                                                             \
        pbase += NPIX;                                                          \
    }

// grid = (24 bands, 2 o-halves, 16 batches), block = 256 (4 waves).
// Wave = 2 o-groups x 32 px; each o-group walks 16 channels.
__global__ __launch_bounds__(256) void ltc_kernel(
    const float*  __restrict__ x,     // [B][64][48][48]
    const float4* __restrict__ meta,  // [OUT_CH(+pad)][9]
    float*        __restrict__ out)   // [B][OUT_CH][48][48]
{
    __shared__ float lds[LDS_DW];

    const int band  = blockIdx.x;     // 0..23
    const int ohalf = blockIdx.y;     // 0..1
    const int b     = blockIdx.z;     // 0..15
    const int r0    = band * 2;
    const int tid   = threadIdx.x;

    // ---- stage 4-row halo as float2, layout [c][4][52], image col gc at col gc+2 ----
    const float* xb = x + (size_t)b * IN_CH * NPIX;
    for (int it = tid; it < NITEMS; it += 256) {
        int c   = it / 104;                 // 104 = 4 rows * 26 pairs
        int rem = it - c * 104;
        int r4  = rem / 26;
        int p   = rem - r4 * 26;            // pair index: cols 2p,2p+1
        int gr  = r0 - 1 + r4;
        float2 v = make_float2(0.f, 0.f);
        if (p > 0 && p < 25 && (unsigned)gr < NH)
            v = *reinterpret_cast<const float2*>(xb + (c * NH + gr) * NW + (2 * p - 2));
        *reinterpret_cast<float2*>(&lds[c * CH_STRIDE + r4 * ROW_STRIDE + 2 * p]) = v;
    }
    __syncthreads();

    const int lane = tid & 63;
    const int wid  = tid >> 6;               // 0..3
    const int og   = lane >> 5;              // 0..1
    const int pxg  = lane & 31;              // 0..31
    const int o0   = ohalf * 128 + (wid * 2 + og) * 16;   // this lane's first channel

    // per-lane pixel bases for the 3 px-groups (96 px = 2 rows x 48)
    int bases[3], opx[3];
#pragma unroll
    for (int g = 0; g < 3; ++g) {
        int px = g * 32 + pxg;               // 0..95
        int rr = (px >= 48) ? 1 : 0;
        int cc = px - rr * 48;
        bases[g] = rr * ROW_STRIDE + cc + 1; // +1: image col gc lives at lds col gc+2, gather col = cc+dj-1
        opx[g]   = (r0 + rr) * NW + cc;
    }

    const float4* mptr = meta + (size_t)o0 * META_F4;
    float*        pbase = out + ((size_t)b * OUT_CH + o0) * NPIX;

    float4 A[9], Bv[9];
#pragma unroll
    for (int q = 0; q < 9; ++q) A[q] = mptr[q];

#pragma unroll 1
    for (int i = 0; i < 8; ++i) {
        LTC_BODY(A, Bv)
        LTC_BODY(Bv, A)
    }
}

extern "C" void kernel_launch(void* const* d_in, const int* in_sizes, int n_in,
                              void* d_out, int out_size, void* d_ws, size_t ws_size,
                              hipStream_t stream) {
    const float* x        = (const float*)d_in[0];
    const float* logits   = (const float*)d_in[1];
    const int*   leaf_idx = (const int*)d_in[2];
    float*       out      = (float*)d_out;
    // meta: 256 records + 16 pad records (harmless prefetch overrun) = 272*144 B
    float*       meta     = (float*)d_ws;

    prep_kernel<<<15, 256, 0, stream>>>(logits, leaf_idx, meta);

    dim3 grid(24, 2, NB);
    ltc_kernel<<<grid, 256, 0, stream>>>(x, (const float4*)meta, out);
}

// Round 6
// 33.488 us; speedup vs baseline: 2.6917x; 1.1480x over previous
//
#include <hip/hip_runtime.h>

#define NB 16
#define IN_CH 64
#define OUT_CH 256
#define NH 48
#define NW 48
#define NPIX (NH * NW)                 // 2304
#define ROW_STRIDE 52                  // dwords per staged row
#define CH_STRIDE (4 * ROW_STRIDE)     // 208 dwords per channel (4 halo rows)
#define LDS_DW (IN_CH * CH_STRIDE)     // 13312 dwords = 53,248 B -> 3 blocks/CU
#define NITEMS (IN_CH * 4 * 26)        // 6656 float2 staging items
#define META_F4 9                      // 9 float4 per o: [0..1]=8 int offsets, [2..8]=7 nodes

__constant__ float c_gate[16 * 4] = {
    0.f, 0.f, 0.f, 0.f,
    0.f, 0.f, 0.f, 1.f,
    0.f, 1.f, 0.f, -1.f,
    0.f, 1.f, 0.f, 0.f,
    0.f, 0.f, 1.f, -1.f,
    0.f, 0.f, 1.f, 0.f,
    0.f, 1.f, 1.f, -2.f,
    0.f, 1.f, 1.f, -1.f,
    1.f, -1.f, -1.f, 1.f,
    1.f, -1.f, -1.f, 2.f,
    1.f, 0.f, -1.f, 0.f,
    1.f, 0.f, -1.f, 1.f,
    1.f, -1.f, 0.f, 0.f,
    1.f, -1.f, 0.f, 1.f,
    1.f, 0.f, 0.f, -1.f,
    1.f, 0.f, 0.f, 0.f
};

// meta[o][36 dw]: dwords 0..7 = int LDS offsets (c*CH_STRIDE+di*ROW_STRIDE+dj),
//                dwords 8..35 = 7 nodes x 4 floats (softmax @ GATE_COEFF)
__global__ __launch_bounds__(256) void prep_kernel(
    const float* __restrict__ logits,
    const int*   __restrict__ leaf_idx,
    float*       __restrict__ meta)
{
    int t = blockIdx.x * 256 + threadIdx.x;
    if (t < OUT_CH * 8) {
        int idx = leaf_idx[t];
        int c  = idx / 9;
        int k  = idx - c * 9;
        int di = k / 3;
        int dj = k - di * 3;
        reinterpret_cast<int*>(meta)[(t >> 3) * 36 + (t & 7)] =
            c * CH_STRIDE + di * ROW_STRIDE + dj;
    } else {
        int t2 = t - OUT_CH * 8;
        if (t2 >= OUT_CH * 7) return;
        int o = t2 / 7;
        int n = t2 - o * 7;
        const float* lg = logits + (size_t)t2 * 16;

        float m = lg[0];
#pragma unroll
        for (int g = 1; g < 16; ++g) m = fmaxf(m, lg[g]);
        float e16[16];
        float s = 0.f;
#pragma unroll
        for (int g = 0; g < 16; ++g) { e16[g] = expf(lg[g] - m); s += e16[g]; }
        float inv = 1.f / s;

        float w0 = 0.f, w1 = 0.f, w2 = 0.f, w3 = 0.f;
#pragma unroll
        for (int g = 0; g < 16; ++g) {
            float p = e16[g] * inv;
            w0 += p * c_gate[g * 4 + 0];
            w1 += p * c_gate[g * 4 + 1];
            w2 += p * c_gate[g * 4 + 2];
            w3 += p * c_gate[g * 4 + 3];
        }
        float* mw = meta + o * 36 + 8 + n * 4;
        mw[0] = w0; mw[1] = w1; mw[2] = w2; mw[3] = w3;
    }
}

// grid = (24 bands, 2 o-halves, 16 batches), block = 512 (8 waves).
// 3 blocks/CU (LDS 53KB) x 8 waves = 24 waves/CU; device-wide exactly one
// generation (6144 waves / 1024 SIMDs = 6/SIMD) -> TLP hides meta+LDS latency.
// Wave = 2 o-groups x 32 px lanes; each o-group walks 8 channels.
__global__ __launch_bounds__(512, 6) void ltc_kernel(
    const float*  __restrict__ x,     // [B][64][48][48]
    const float4* __restrict__ meta,  // [OUT_CH][9]
    float*        __restrict__ out)   // [B][OUT_CH][48][48]
{
    __shared__ float lds[LDS_DW];

    const int band  = blockIdx.x;     // 0..23
    const int ohalf = blockIdx.y;     // 0..1
    const int b     = blockIdx.z;     // 0..15
    const int r0    = band * 2;
    const int tid   = threadIdx.x;

    // ---- stage 4-row halo as float2: layout [c][4][52], image col gc at gc+2 ----
    const float* xb = x + (size_t)b * IN_CH * NPIX;
    for (int it = tid; it < NITEMS; it += 512) {
        int c   = it / 104;                 // 104 = 4 rows * 26 pairs
        int rem = it - c * 104;
        int r4  = rem / 26;
        int p   = rem - r4 * 26;            // pair: cols 2p, 2p+1
        int gr  = r0 - 1 + r4;
        float2 v = make_float2(0.f, 0.f);
        if (p > 0 && p < 25 && (unsigned)gr < NH)
            v = *reinterpret_cast<const float2*>(xb + (c * NH + gr) * NW + (2 * p - 2));
        *reinterpret_cast<float2*>(&lds[c * CH_STRIDE + r4 * ROW_STRIDE + 2 * p]) = v;
    }
    __syncthreads();

    const int lane = tid & 63;
    const int wid  = tid >> 6;               // 0..7
    const int og   = lane >> 5;              // 0..1
    const int pxg  = lane & 31;              // 0..31
    const int o0   = ohalf * 128 + ((wid << 1) | og) * 8;  // first of 8 channels

    // per-lane pixel bases for 3 px-groups (96 px = 2 rows x 48)
    int bases[3], opx[3];
#pragma unroll
    for (int g = 0; g < 3; ++g) {
        int px = g * 32 + pxg;               // 0..95
        int rr = (px >= 48) ? 1 : 0;
        int cc = px - rr * 48;
        bases[g] = rr * ROW_STRIDE + cc + 1; // gather col = cc + dj - 1 (+2 shift)
        opx[g]   = (r0 + rr) * NW + cc;
    }

    const float4* mptr  = meta + (size_t)o0 * META_F4;
    float*        pbase = out + ((size_t)b * OUT_CH + o0) * NPIX;

#pragma unroll 2
    for (int i = 0; i < 8; ++i) {
        float4 M[9];
#pragma unroll
        for (int q = 0; q < 9; ++q) M[q] = mptr[q];

        const int off0 = __float_as_int(M[0].x);
        const int off1 = __float_as_int(M[0].y);
        const int off2 = __float_as_int(M[0].z);
        const int off3 = __float_as_int(M[0].w);
        const int off4 = __float_as_int(M[1].x);
        const int off5 = __float_as_int(M[1].y);
        const int off6 = __float_as_int(M[1].z);
        const int off7 = __float_as_int(M[1].w);

#pragma unroll
        for (int g = 0; g < 3; ++g) {
            const int bg = bases[g];
            float v0 = lds[off0 + bg];
            float v1 = lds[off1 + bg];
            float v2 = lds[off2 + bg];
            float v3 = lds[off3 + bg];
            float v4 = lds[off4 + bg];
            float v5 = lds[off5 + bg];
            float v6 = lds[off6 + bg];
            float v7 = lds[off7 + bg];
            float t0 = fmaf(v1, fmaf(M[2].w, v0, M[2].z), fmaf(M[2].y, v0, M[2].x));
            float t1 = fmaf(v3, fmaf(M[3].w, v2, M[3].z), fmaf(M[3].y, v2, M[3].x));
            float t2 = fmaf(v5, fmaf(M[4].w, v4, M[4].z), fmaf(M[4].y, v4, M[4].x));
            float t3 = fmaf(v7, fmaf(M[5].w, v6, M[5].z), fmaf(M[5].y, v6, M[5].x));
            float u0 = fmaf(t1, fmaf(M[6].w, t0, M[6].z), fmaf(M[6].y, t0, M[6].x));
            float u1 = fmaf(t3, fmaf(M[7].w, t2, M[7].z), fmaf(M[7].y, t2, M[7].x));
            float y  = fmaf(u1, fmaf(M[8].w, u0, M[8].z), fmaf(M[8].y, u0, M[8].x));
            pbase[opx[g]] = y;
        }
        mptr  += META_F4;
        pbase += NPIX;
    }
}

extern "C" void kernel_launch(void* const* d_in, const int* in_sizes, int n_in,
                              void* d_out, int out_size, void* d_ws, size_t ws_size,
                              hipStream_t stream) {
    const float* x        = (const float*)d_in[0];
    const float* logits   = (const float*)d_in[1];
    const int*   leaf_idx = (const int*)d_in[2];
    float*       out      = (float*)d_out;
    float*       meta     = (float*)d_ws;    // 256*36 dwords = 36,864 B

    prep_kernel<<<15, 256, 0, stream>>>(logits, leaf_idx, meta);

    dim3 grid(24, 2, NB);
    ltc_kernel<<<grid, 512, 0, stream>>>(x, (const float4*)meta, out);
}